// Round 1
// baseline (240.821 us; speedup 1.0000x reference)
//
#include <hip/hip_runtime.h>
#include <math.h>

#define C_   128
#define NQ_  8
#define NK_  32768
#define L3C_ 384

// ws layout (float offsets)
#define AQ_OFF     0        // 1024
#define MINP_OFF   1024     // 512
#define MAXP_OFF   1536     // 8*512
#define FLOOR_OFF  5632     // 1
#define ROWMAX_OFF 5633     // 8
#define DENOM_OFF  5644     // 8*256
#define OUTV_OFF   7692     // 256*1024
// total ~1.04 MB of ws

__device__ inline float wredmin(float v){
#pragma unroll
  for(int o=32;o>0;o>>=1) v=fminf(v,__shfl_xor(v,o,64));
  return v;
}
__device__ inline float wredmax(float v){
#pragma unroll
  for(int o=32;o>0;o>>=1) v=fmaxf(v,__shfl_xor(v,o,64));
  return v;
}
__device__ inline float wredsum(float v){
#pragma unroll
  for(int o=32;o>0;o>>=1) v+=__shfl_xor(v,o,64);
  return v;
}

// Kernel 1: Aq[o][q] = b1[o] + sum_c W1[o][c]*query[c][q]
__global__ __launch_bounds__(128) void aq_kernel(const float* __restrict__ query,
    const float* __restrict__ W1, const float* __restrict__ b1,
    float* __restrict__ ws){
  const int o = threadIdx.x;
#pragma unroll
  for(int q=0;q<NQ_;q++){
    float s = b1[o];
    for(int c=0;c<C_;c++) s += W1[o*L3C_+c]*query[c*NQ_+q];
    ws[AQ_OFF + o*NQ_ + q] = s;
  }
}

// Kernel 2: raw scores for a 64-wide k-tile, all 8 q. Register-blocked 8(o)x4(kl) GEMM.
__global__ __launch_bounds__(256) void scores_kernel(
    const float* __restrict__ keys, const float* __restrict__ dist,
    const int* __restrict__ mask, const float* __restrict__ W1,
    const float* __restrict__ W2, const float* __restrict__ b2p,
    float* __restrict__ ws, float* __restrict__ scores)
{
  __shared__ __align__(16) float w1T[128][132];   // [c][o], padded
  __shared__ __align__(16) float bk[128*64];      // [o][kl]
  __shared__ __align__(16) float tile[128*64];    // [c][kl] (keys, then dist)
  __shared__ __align__(16) float aq_s[1024];      // [o][q]
  __shared__ __align__(16) float red[64*17];      // [kl][to] padded

  const int t   = threadIdx.x;
  const int kb  = blockIdx.x;
  const int k0  = kb*64;
  const int to  = t>>4, tkl = t&15;
  const int o0  = to*8, kl0 = tkl*4;

  for(int i=t;i<1024;i+=256) aq_s[i]=ws[AQ_OFF+i];
  for(int i=t;i<16384;i+=256){int o=i>>7,c=i&127; w1T[c][o]=W1[o*L3C_+128+c];}
  for(int i=t;i<2048;i+=256){int c=i>>4,k4=(i&15)*4;
    *(float4*)&tile[c*64+k4] = *(const float4*)&keys[(size_t)c*NK_+k0+k4];}
  __syncthreads();

  // Bk tile = W1k * keys_tile
  {
    float acc[8][4]={};
#pragma unroll 4
    for(int c=0;c<128;c++){
      const float4 a0=*(const float4*)&w1T[c][o0];
      const float4 a1=*(const float4*)&w1T[c][o0+4];
      const float4 b =*(const float4*)&tile[c*64+kl0];
      const float av[8]={a0.x,a0.y,a0.z,a0.w,a1.x,a1.y,a1.z,a1.w};
      const float bv[4]={b.x,b.y,b.z,b.w};
#pragma unroll
      for(int j=0;j<8;j++)
#pragma unroll
        for(int jj=0;jj<4;jj++) acc[j][jj]+=av[j]*bv[jj];
    }
#pragma unroll
    for(int j=0;j<8;j++)
      *(float4*)&bk[(o0+j)*64+kl0]=make_float4(acc[j][0],acc[j][1],acc[j][2],acc[j][3]);
  }
  __syncthreads();
  // overwrite w1T with dist-part weights
  for(int i=t;i<16384;i+=256){int o=i>>7,c=i&127; w1T[c][o]=W1[o*L3C_+256+c];}

  float w2r[8];
#pragma unroll
  for(int j=0;j<8;j++) w2r[j]=W2[o0+j];
  const float b2v=b2p[0];
  float minrun=INFINITY;

  for(int q=0;q<NQ_;q++){
    __syncthreads();   // w1T ready (q=0); prev iter readers of tile/red done (q>0)
    {
      const size_t qoff=(size_t)q*NK_;
      for(int i=t;i<2048;i+=256){int c=i>>4,k4=(i&15)*4;
        *(float4*)&tile[c*64+k4] = *(const float4*)&dist[(size_t)c*(NQ_*(size_t)NK_)+qoff+k0+k4];}
    }
    __syncthreads();

    float acc[8][4]={};
#pragma unroll 4
    for(int c=0;c<128;c++){
      const float4 a0=*(const float4*)&w1T[c][o0];
      const float4 a1=*(const float4*)&w1T[c][o0+4];
      const float4 b =*(const float4*)&tile[c*64+kl0];
      const float av[8]={a0.x,a0.y,a0.z,a0.w,a1.x,a1.y,a1.z,a1.w};
      const float bv[4]={b.x,b.y,b.z,b.w};
#pragma unroll
      for(int j=0;j<8;j++)
#pragma unroll
        for(int jj=0;jj<4;jj++) acc[j][jj]+=av[j]*bv[jj];
    }

    float partial[4]={0.f,0.f,0.f,0.f};
#pragma unroll
    for(int j=0;j<8;j++){
      const float aqv=aq_s[(o0+j)*NQ_+q];
      const float4 bkv=*(const float4*)&bk[(o0+j)*64+kl0];
      const float bka[4]={bkv.x,bkv.y,bkv.z,bkv.w};
#pragma unroll
      for(int jj=0;jj<4;jj++){
        const float p=acc[j][jj]+aqv+bka[jj];
        partial[jj]+=w2r[j]*fmaxf(p,0.0f);
      }
    }
#pragma unroll
    for(int jj=0;jj<4;jj++) red[(kl0+jj)*17+to]=partial[jj];
    __syncthreads();

    if(t<64){ // wave 0
      float s=b2v;
#pragma unroll
      for(int g=0;g<16;g++) s+=red[t*17+g];
      scores[(size_t)q*NK_+k0+t]=s;                     // raw scores (masked later)
      minrun=fminf(minrun,wredmin(s));
      const int m=mask[(size_t)q*NK_+k0+t];
      const float mx=wredmax(m? s : -INFINITY);
      if(t==0) ws[MAXP_OFF+q*512+kb]=mx;
    }
  }
  if(t==0) ws[MINP_OFF+kb]=minrun;
}

// Kernel 3: reduce partials -> floor, rowmax[8]
__global__ __launch_bounds__(512) void minmax_kernel(float* __restrict__ ws){
  const int t=threadIdx.x, w=t>>6, l=t&63;
  float mx=-INFINITY;
  for(int i=l;i<512;i+=64) mx=fmaxf(mx,ws[MAXP_OFF+w*512+i]);
  mx=wredmax(mx);
  if(l==0) ws[ROWMAX_OFF+w]=mx;
  if(w==0){
    float mn=INFINITY;
    for(int i=l;i<512;i+=64) mn=fminf(mn,ws[MINP_OFF+i]);
    mn=wredmin(mn);
    if(l==0) ws[FLOOR_OFF]=mn-20.0f;
  }
}

// Kernel 4: per 128-wide chunk: mask in place, exp, denom partial, e*V^T partial
__global__ __launch_bounds__(256) void softmax_pv_kernel(
    const float* __restrict__ value, const int* __restrict__ mask,
    float* __restrict__ scores, float* __restrict__ ws)
{
  __shared__ __align__(16) float v_lds[128][129];
  __shared__ __align__(16) float e_lds[8][128];
  __shared__ float wsum[8][2];
  const int t=threadIdx.x, bid=blockIdx.x, k0=bid*128;
  const float floorv=ws[FLOOR_OFF];

  for(int i=t;i<4096;i+=256){int d=i>>5,k4=(i&31)*4;
    const float4 v=*(const float4*)&value[(size_t)d*NK_+k0+k4];
    v_lds[d][k4]=v.x; v_lds[d][k4+1]=v.y; v_lds[d][k4+2]=v.z; v_lds[d][k4+3]=v.w;}

  const int w=t>>6, l=t&63;
#pragma unroll
  for(int it=0;it<4;it++){
    const int i=t+256*it, q=i>>7, k=i&127;
    const size_t gi=(size_t)q*NK_+k0+k;
    const float s=scores[gi];
    const int m=mask[gi];
    const float sf=m? s : s+floorv;
    scores[gi]=sf;                                  // final (masked) scores output
    const float e=expf(sf-ws[ROWMAX_OFF+q]);
    e_lds[q][k]=e;
    const float es=wredsum(e);
    if(l==0) wsum[q][w&1]=es;
  }
  __syncthreads();
  if(t<8) ws[DENOM_OFF+t*256+bid]=wsum[t][0]+wsum[t][1];

  const int d=t&127, qb=(t>>7)*4;
  float acc[4]={0.f,0.f,0.f,0.f};
  for(int k=0;k<128;k++){
    const float v=v_lds[d][k];
#pragma unroll
    for(int j=0;j<4;j++) acc[j]+=e_lds[qb+j][k]*v;
  }
#pragma unroll
  for(int j=0;j<4;j++) ws[OUTV_OFF+(size_t)bid*1024+d*8+qb+j]=acc[j];
}

// Kernel 5: reduce chunk partials, divide by denom
__global__ __launch_bounds__(1024) void finalize_kernel(const float* __restrict__ ws,
    float* __restrict__ out){
  __shared__ float dn[8];
  const int t=threadIdx.x;
  if(t<8){float s=0.f; for(int c=0;c<256;c++) s+=ws[DENOM_OFF+t*256+c]; dn[t]=s;}
  __syncthreads();
  float a=0.f;
  for(int c=0;c<256;c++) a+=ws[OUTV_OFF+(size_t)c*1024+t];
  out[t]=a/dn[t&7];
}

extern "C" void kernel_launch(void* const* d_in, const int* in_sizes, int n_in,
                              void* d_out, int out_size, void* d_ws, size_t ws_size,
                              hipStream_t stream){
  const float* query=(const float*)d_in[0];
  const float* keys =(const float*)d_in[1];
  const float* value=(const float*)d_in[2];
  const float* dist =(const float*)d_in[3];
  const int*   mask =(const int*)d_in[4];
  const float* W1   =(const float*)d_in[5];
  const float* b1   =(const float*)d_in[6];
  const float* W2   =(const float*)d_in[7];
  const float* b2   =(const float*)d_in[8];
  float* out=(float*)d_out;
  float* scores=out+1024;          // output 1 region
  float* ws=(float*)d_ws;

  aq_kernel       <<<1,128,0,stream>>>(query,W1,b1,ws);
  scores_kernel   <<<512,256,0,stream>>>(keys,dist,mask,W1,W2,b2,ws,scores);
  minmax_kernel   <<<1,512,0,stream>>>(ws);
  softmax_pv_kernel<<<256,256,0,stream>>>(value,mask,scores,ws);
  finalize_kernel <<<1,1024,0,stream>>>(ws,out);
}

// Round 2
// 95.659 us; speedup vs baseline: 2.5175x; 2.5175x over previous
//
#include <hip/hip_runtime.h>
#include <math.h>

#define C_    128
#define NQ_   8
#define NK_   32768
#define QNK_  (NQ_*NK_)
#define KT_   32
#define NBLK_ (NK_/KT_)   // 1024

// ws float offsets
#define AQ_OFF     0        // [q][o] 1024
#define MINP_OFF   1024     // 1024
#define MAXP_OFF   2048     // 8*1024 -> ends 10240
#define FLOOR_OFF  10240
#define ROWMAX_OFF 10241    // 8
#define DENOM_OFF  10256    // 8*256 -> 12304
#define OUTV_OFF   12304    // 256*1024 -> 274448
#define WSA_OFF    274448   // bf16 A-frag region: 32768 shorts (16384 floats)

typedef float f32x4 __attribute__((ext_vector_type(4)));
typedef short bf16x8 __attribute__((ext_vector_type(8)));

__device__ inline unsigned short f2bf(float f){
  unsigned u = __float_as_uint(f);
  return (unsigned short)((u + 0x7FFFu + ((u >> 16) & 1u)) >> 16);  // RNE
}

__device__ inline float wredmin(float v){
#pragma unroll
  for(int o=32;o>0;o>>=1) v=fminf(v,__shfl_xor(v,o,64));
  return v;
}
__device__ inline float wredmax(float v){
#pragma unroll
  for(int o=32;o>0;o>>=1) v=fmaxf(v,__shfl_xor(v,o,64));
  return v;
}
__device__ inline float wredsum(float v){
#pragma unroll
  for(int o=32;o>0;o>>=1) v+=__shfl_xor(v,o,64);
  return v;
}

// ---------------- prep: Aq (fp32) + bf16 A-fragment table ----------------
// A-frag table: frag F = w*16 + (part*8 + ks*2 + of); element E = F*512 + lane*8 + e
// holds W1[o=32w+16of+(lane&15)][128 + 128*part + 32ks + 8*(lane>>4) + e] as bf16.
__global__ __launch_bounds__(256) void prep_kernel(const float* __restrict__ query,
    const float* __restrict__ W1, const float* __restrict__ b1, float* __restrict__ ws){
  const int t = threadIdx.x;
  unsigned int* wsa = (unsigned int*)(ws + WSA_OFF);
  for (int u = t; u < 16384; u += 256){
    unsigned int pack = 0;
#pragma unroll
    for (int e2 = 0; e2 < 2; e2++){
      const int E = u*2 + e2;
      const int f = E >> 9, lane = (E >> 3) & 63, e = E & 7;
      const int w = f >> 4, r = f & 15;
      const int part = r >> 3, ks = (r >> 1) & 3, of = r & 1;
      const int o = w*32 + of*16 + (lane & 15);
      const int c = ks*32 + ((lane >> 4) << 3) + e;
      const float v = W1[o*384 + 128 + part*128 + c];
      pack |= (unsigned int)f2bf(v) << (16*e2);
    }
    wsa[u] = pack;
  }
  if (t < 128){
    const int o = t;
    float s[8];
#pragma unroll
    for (int q = 0; q < 8; q++) s[q] = b1[o];
    for (int c = 0; c < 128; c++){
      const float wv = W1[o*384 + c];
#pragma unroll
      for (int q = 0; q < 8; q++) s[q] += wv * query[c*8 + q];
    }
#pragma unroll
    for (int q = 0; q < 8; q++) ws[AQ_OFF + q*128 + o] = s[q];
  }
}

// ---------------- staging helpers (fp32 global -> swizzled bf16 LDS [kl][c]) ----
__device__ inline void stage_load(const float* __restrict__ src, size_t rstride,
                                  int scp, int skl4, float4* ra, float4* rb){
#pragma unroll
  for (int i = 0; i < 2; i++){
    const int c = 2*scp + 64*i;
    ra[i] = *(const float4*)(src + (size_t)c*rstride + skl4);
    rb[i] = *(const float4*)(src + (size_t)(c+1)*rstride + skl4);
  }
}
__device__ inline void stage_write(unsigned short* __restrict__ lds,
                                   int scp, int skl4, const float4* ra, const float4* rb){
#pragma unroll
  for (int i = 0; i < 2; i++){
    const int c = 2*scp + 64*i;
    const float av[4] = {ra[i].x, ra[i].y, ra[i].z, ra[i].w};
    const float bv[4] = {rb[i].x, rb[i].y, rb[i].z, rb[i].w};
#pragma unroll
    for (int j = 0; j < 4; j++){
      const int kl = skl4 + j;
      const int idx = (kl*128 + c) ^ ((kl & 7) << 3);   // XOR-swizzle (G4)
      *(unsigned int*)&lds[idx] = (unsigned int)f2bf(av[j]) | ((unsigned int)f2bf(bv[j]) << 16);
    }
  }
}
__device__ inline bf16x8 frag_read(const unsigned short* __restrict__ lds,
                                   int cf, int ks, int g, int li){
  const int idx = ((((cf<<4) + li)<<7) + (ks<<5) + (g<<3)) ^ ((li & 7) << 3);
  return *(const bf16x8*)&lds[idx];
}

// ---------------- scores: MFMA over o-slices, keys folded once ----------------
__global__ __launch_bounds__(256, 2) void scores_kernel(
    const float* __restrict__ keys, const float* __restrict__ dist,
    const int* __restrict__ mask, const float* __restrict__ W2,
    const float* __restrict__ b2p, float* __restrict__ ws,
    float* __restrict__ scores)
{
  __shared__ unsigned short k_lds[KT_*128];
  __shared__ unsigned short d_lds[2][KT_*128];
  __shared__ float aq_lds[NQ_*128];
  __shared__ float red[4][KT_];

  const int t = threadIdx.x, w = t >> 6, l = t & 63;
  const int g = l >> 4, li = l & 15;
  const int blk = blockIdx.x, k0 = blk * KT_;
  const int o0 = w * 32;

  // A fragments: held in registers for the whole kernel (64 VGPRs)
  const bf16x8* wsa8 = (const bf16x8*)((const char*)ws + (size_t)WSA_OFF*4);
  bf16x8 afr[16];
#pragma unroll
  for (int f = 0; f < 16; f++) afr[f] = wsa8[(w*16 + f)*64 + l];

  const f32x4 w2v0 = *(const f32x4*)&W2[o0 + (g<<2)];
  const f32x4 w2v1 = *(const f32x4*)&W2[o0 + 16 + (g<<2)];
  const float b2v = b2p[0];

  for (int i = t; i < NQ_*128; i += 256) aq_lds[i] = ws[AQ_OFF + i];

  const int skl4 = (t & 7) * 4;
  const int scp  = t >> 3;

  float4 ra[2], rb[2], ka[2], kb[2];
  stage_load(keys + k0, NK_, scp, skl4, ka, kb);
  stage_load(dist + k0, QNK_, scp, skl4, ra, rb);    // q=0
  stage_write(k_lds, scp, skl4, ka, kb);
  __syncthreads();                                   // k_lds + aq_lds ready

  // Bk accumulators (keys part), reused for all 8 q
  f32x4 bk[2][2];
#pragma unroll
  for (int cf = 0; cf < 2; cf++)
#pragma unroll
    for (int of = 0; of < 2; of++){ f32x4 z = {0.f,0.f,0.f,0.f}; bk[cf][of] = z; }
#pragma unroll
  for (int ks = 0; ks < 4; ks++){
#pragma unroll
    for (int cf = 0; cf < 2; cf++){
      const bf16x8 b = frag_read(k_lds, cf, ks, g, li);
      bk[cf][0] = __builtin_amdgcn_mfma_f32_16x16x32_bf16(afr[ks*2+0], b, bk[cf][0], 0,0,0);
      bk[cf][1] = __builtin_amdgcn_mfma_f32_16x16x32_bf16(afr[ks*2+1], b, bk[cf][1], 0,0,0);
    }
  }

  stage_write(d_lds[0], scp, skl4, ra, rb);
  stage_load(dist + NK_ + k0, QNK_, scp, skl4, ra, rb);  // q=1
  __syncthreads();                                        // d_lds[0] ready

  float minv = INFINITY;

  for (int q = 0; q < NQ_; q++){
    const unsigned short* db = d_lds[q & 1];
    f32x4 acc[2][2];
#pragma unroll
    for (int cf = 0; cf < 2; cf++)
#pragma unroll
      for (int of = 0; of < 2; of++) acc[cf][of] = bk[cf][of];

#pragma unroll
    for (int ks = 0; ks < 4; ks++){
#pragma unroll
      for (int cf = 0; cf < 2; cf++){
        const bf16x8 b = frag_read(db, cf, ks, g, li);
        acc[cf][0] = __builtin_amdgcn_mfma_f32_16x16x32_bf16(afr[8+ks*2+0], b, acc[cf][0], 0,0,0);
        acc[cf][1] = __builtin_amdgcn_mfma_f32_16x16x32_bf16(afr[8+ks*2+1], b, acc[cf][1], 0,0,0);
      }
    }

    // epilogue: s(col) = sum_o W2[o]*relu(H + Aq)
    const f32x4 aqv0 = *(const f32x4*)&aq_lds[q*128 + o0 + (g<<2)];
    const f32x4 aqv1 = *(const f32x4*)&aq_lds[q*128 + o0 + 16 + (g<<2)];
#pragma unroll
    for (int cf = 0; cf < 2; cf++){
      float s = 0.f;
#pragma unroll
      for (int r = 0; r < 4; r++){
        s += w2v0[r] * fmaxf(acc[cf][0][r] + aqv0[r], 0.f);
        s += w2v1[r] * fmaxf(acc[cf][1][r] + aqv1[r], 0.f);
      }
      s += __shfl_xor(s, 16, 64);
      s += __shfl_xor(s, 32, 64);
      if (l < 16) red[w][(cf<<4) + l] = s;
    }
    __syncthreads();                                  // red ready; db reads done

    if (q < 7){
      stage_write(d_lds[(q+1)&1], scp, skl4, ra, rb); // waits q+1 loads
      if (q < 6) stage_load(dist + (size_t)(q+2)*NK_ + k0, QNK_, scp, skl4, ra, rb);
    }
    if (t < 32){
      float s = b2v + red[0][t] + red[1][t] + red[2][t] + red[3][t];
      scores[(size_t)q*NK_ + k0 + t] = s;             // raw scores (masked later)
      minv = fminf(minv, s);
      float mx = mask[(size_t)q*NK_ + k0 + t] ? s : -INFINITY;
#pragma unroll
      for (int off = 16; off > 0; off >>= 1) mx = fmaxf(mx, __shfl_xor(mx, off, 64));
      if (t == 0) ws[MAXP_OFF + q*NBLK_ + blk] = mx;
    }
    __syncthreads();                                  // next buf ready; red free
  }

  if (t < 32){
#pragma unroll
    for (int off = 16; off > 0; off >>= 1) minv = fminf(minv, __shfl_xor(minv, off, 64));
    if (t == 0) ws[MINP_OFF + blk] = minv;
  }
}

// ---------------- reduce partials -> floor, rowmax[8] ----------------
__global__ __launch_bounds__(512) void minmax_kernel(float* __restrict__ ws){
  const int t=threadIdx.x, w=t>>6, l=t&63;
  float mx=-INFINITY;
  for(int i=l;i<NBLK_;i+=64) mx=fmaxf(mx,ws[MAXP_OFF+w*NBLK_+i]);
  mx=wredmax(mx);
  if(l==0) ws[ROWMAX_OFF+w]=mx;
  if(w==0){
    float mn=INFINITY;
    for(int i=l;i<NBLK_;i+=64) mn=fminf(mn,ws[MINP_OFF+i]);
    mn=wredmin(mn);
    if(l==0) ws[FLOOR_OFF]=mn-20.0f;
  }
}

// ---------------- softmax + PV partials ----------------
__global__ __launch_bounds__(256) void softmax_pv_kernel(
    const float* __restrict__ value, const int* __restrict__ mask,
    float* __restrict__ scores, float* __restrict__ ws)
{
  __shared__ __align__(16) float v_lds[128][129];
  __shared__ __align__(16) float e_lds[8][128];
  __shared__ float wsum[8][2];
  const int t=threadIdx.x, bid=blockIdx.x, k0=bid*128;
  const float floorv=ws[FLOOR_OFF];

  for(int i=t;i<4096;i+=256){int d=i>>5,k4=(i&31)*4;
    const float4 v=*(const float4*)&value[(size_t)d*NK_+k0+k4];
    v_lds[d][k4]=v.x; v_lds[d][k4+1]=v.y; v_lds[d][k4+2]=v.z; v_lds[d][k4+3]=v.w;}

  const int w=t>>6, l=t&63;
#pragma unroll
  for(int it=0;it<4;it++){
    const int i=t+256*it, q=i>>7, k=i&127;
    const size_t gi=(size_t)q*NK_+k0+k;
    const float s=scores[gi];
    const int m=mask[gi];
    const float sf=m? s : s+floorv;
    scores[gi]=sf;                                  // final (masked) scores output
    const float e=expf(sf-ws[ROWMAX_OFF+q]);
    e_lds[q][k]=e;
    const float es=wredsum(e);
    if(l==0) wsum[q][w&1]=es;
  }
  __syncthreads();
  if(t<8) ws[DENOM_OFF+t*256+bid]=wsum[t][0]+wsum[t][1];

  const int d=t&127, qb=(t>>7)*4;
  float acc[4]={0.f,0.f,0.f,0.f};
  for(int k=0;k<128;k++){
    const float v=v_lds[d][k];
#pragma unroll
    for(int j=0;j<4;j++) acc[j]+=e_lds[qb+j][k]*v;
  }
#pragma unroll
  for(int j=0;j<4;j++) ws[OUTV_OFF+(size_t)bid*1024+d*8+qb+j]=acc[j];
}

// ---------------- final reduce ----------------
__global__ __launch_bounds__(1024) void finalize_kernel(const float* __restrict__ ws,
    float* __restrict__ out){
  __shared__ float dn[8];
  const int t=threadIdx.x;
  if(t<8){float s=0.f; for(int c=0;c<256;c++) s+=ws[DENOM_OFF+t*256+c]; dn[t]=s;}
  __syncthreads();
  float a=0.f;
  for(int c=0;c<256;c++) a+=ws[OUTV_OFF+(size_t)c*1024+t];
  out[t]=a/dn[t&7];
}

extern "C" void kernel_launch(void* const* d_in, const int* in_sizes, int n_in,
                              void* d_out, int out_size, void* d_ws, size_t ws_size,
                              hipStream_t stream){
  const float* query=(const float*)d_in[0];
  const float* keys =(const float*)d_in[1];
  const float* value=(const float*)d_in[2];
  const float* dist =(const float*)d_in[3];
  const int*   mask =(const int*)d_in[4];
  const float* W1   =(const float*)d_in[5];
  const float* b1   =(const float*)d_in[6];
  const float* W2   =(const float*)d_in[7];
  const float* b2   =(const float*)d_in[8];
  float* out=(float*)d_out;
  float* scores=out+1024;          // output 1 region
  float* ws=(float*)d_ws;

  prep_kernel     <<<1,256,0,stream>>>(query,W1,b1,ws);
  scores_kernel   <<<NBLK_,256,0,stream>>>(keys,dist,mask,W2,b2,ws,scores);
  minmax_kernel   <<<1,512,0,stream>>>(ws);
  softmax_pv_kernel<<<256,256,0,stream>>>(value,mask,scores,ws);
  finalize_kernel <<<1,1024,0,stream>>>(ws,out);
}

// Round 3
// 67.188 us; speedup vs baseline: 3.5843x; 1.4237x over previous
//
#include <hip/hip_runtime.h>
#include <hip/hip_bf16.h>
#include <math.h>

#define C_    128
#define NQ_   8
#define NK_   32768
#define QNK_  (NQ_*NK_)
#define KT_   32
#define NBLK_ (NK_/KT_)   // 1024
#define NCH_  256         // softmax chunks of 128 cols

// ws float offsets
#define AQ_OFF     0        // [q][o] 1024
#define MINKEY_OFF 1024     // 1 uint (order-preserving float key)
#define DENOM_OFF  1040     // 8*256
#define OUTV_OFF   4096     // 256*1024
#define WSA_OFF    266240   // bf16 A-frag table: 32768 shorts (16384 floats)

typedef float f32x4 __attribute__((ext_vector_type(4)));
typedef int   i32x4 __attribute__((ext_vector_type(4)));
typedef short bf16x8 __attribute__((ext_vector_type(8)));

__device__ inline unsigned short f2bf(float f){ // prep only
  unsigned u = __float_as_uint(f);
  return (unsigned short)((u + 0x7FFFu + ((u >> 16) & 1u)) >> 16);
}
__device__ inline unsigned int pkbf(float a, float b){
  __hip_bfloat162 h = __float22bfloat162_rn(make_float2(a, b)); // v_cvt_pk_bf16_f32
  union { __hip_bfloat162 h2; unsigned int u; } cv; cv.h2 = h; return cv.u;
}
__device__ inline unsigned int fkey(float f){   // monotone float->uint
  unsigned u = __float_as_uint(f);
  return (u & 0x80000000u) ? ~u : (u | 0x80000000u);
}
__device__ inline float fkey_dec(unsigned key){
  unsigned u = (key & 0x80000000u) ? (key & 0x7FFFFFFFu) : ~key;
  return __uint_as_float(u);
}
__device__ inline int swz8(int r){ return ((r ^ (r >> 3)) & 7) << 3; } // shorts (16B units)

// ---------------- prep: Aq + bf16 A-frag table + atomic init ----------------
__global__ __launch_bounds__(256) void prep_kernel(const float* __restrict__ query,
    const float* __restrict__ W1, const float* __restrict__ b1, float* __restrict__ ws){
  const int t = threadIdx.x;
  if (t == 0) *(unsigned int*)(ws + MINKEY_OFF) = 0xFFFFFFFFu;
  unsigned int* wsa = (unsigned int*)(ws + WSA_OFF);
  for (int u = t; u < 16384; u += 256){
    unsigned int pack = 0;
#pragma unroll
    for (int e2 = 0; e2 < 2; e2++){
      const int E = u*2 + e2;
      const int f = E >> 9, lane = (E >> 3) & 63, e = E & 7;
      const int w = f >> 4, r = f & 15;
      const int part = r >> 3, ks = (r >> 1) & 3, of = r & 1;
      const int o = w*32 + of*16 + (lane & 15);
      const int c = ks*32 + ((lane >> 4) << 3) + e;
      pack |= (unsigned int)f2bf(W1[o*384 + 128 + part*128 + c]) << (16*e2);
    }
    wsa[u] = pack;
  }
  if (t < 128){
    const int o = t;
    float s[8];
#pragma unroll
    for (int q = 0; q < 8; q++) s[q] = b1[o];
    for (int c = 0; c < 128; c++){
      const float wv = W1[o*384 + c];
#pragma unroll
      for (int q = 0; q < 8; q++) s[q] += wv * query[c*8 + q];
    }
#pragma unroll
    for (int q = 0; q < 8; q++) ws[AQ_OFF + q*128 + o] = s[q];
  }
}

// ---------------- staging (fp32 global -> swizzled bf16 LDS [kl][c]) ----------
template<bool NT>
__device__ inline void stage_load(const float* __restrict__ src, size_t rstride,
                                  int scp, int skl4, f32x4* ra, f32x4* rb){
#pragma unroll
  for (int i = 0; i < 2; i++){
    const float* pa = src + (size_t)(2*scp + 64*i)*rstride + skl4;
    const float* pb = pa + rstride;
    if (NT){ ra[i] = __builtin_nontemporal_load((const f32x4*)pa);
             rb[i] = __builtin_nontemporal_load((const f32x4*)pb); }
    else   { ra[i] = *(const f32x4*)pa; rb[i] = *(const f32x4*)pb; }
  }
}
__device__ inline void stage_write(unsigned short* __restrict__ lds,
                                   int scp, int skl4, const f32x4* ra, const f32x4* rb){
#pragma unroll
  for (int i = 0; i < 2; i++){
    const int c = 2*scp + 64*i;
#pragma unroll
    for (int j = 0; j < 4; j++){
      const int kl = skl4 + j;
      const int idx = (kl*128 + c) ^ swz8(kl);
      *(unsigned int*)&lds[idx] = pkbf(ra[i][j], rb[i][j]);
    }
  }
}
__device__ inline bf16x8 frag_read(const unsigned short* __restrict__ lds,
                                   int cf, int ks, int g, int li){
  const int row = (cf << 4) + li;
  const int idx = (row << 7) + (((ks << 5) + (g << 3)) ^ swz8(row));
  return *(const bf16x8*)&lds[idx];
}

// ---------------- scores ----------------
__global__ __launch_bounds__(256, 3) void scores_kernel(
    const float* __restrict__ keys, const float* __restrict__ dist,
    const float* __restrict__ W2, const float* __restrict__ b2p,
    float* __restrict__ ws, float* __restrict__ scores)
{
  __shared__ unsigned short k_lds[KT_*128];
  __shared__ unsigned short d_lds[2][KT_*128];
  __shared__ float aq_lds[NQ_*128];
  __shared__ float red[4][KT_];

  const int t = threadIdx.x, w = t >> 6, l = t & 63;
  const int g = l >> 4, li = l & 15;
  const int blk = blockIdx.x, k0 = blk * KT_;
  const int o0 = w * 32;

  const bf16x8* wsa8 = (const bf16x8*)(ws + WSA_OFF);
  bf16x8 afr[16];
#pragma unroll
  for (int f = 0; f < 16; f++) afr[f] = wsa8[(w*16 + f)*64 + l];

  const f32x4 w2v0 = *(const f32x4*)&W2[o0 + (g<<2)];
  const f32x4 w2v1 = *(const f32x4*)&W2[o0 + 16 + (g<<2)];
  const float b2v = b2p[0];

  for (int i = t; i < NQ_*128; i += 256) aq_lds[i] = ws[AQ_OFF + i];

  const int skl4 = (t & 7) * 4;
  const int scp  = t >> 3;

  f32x4 ra[2], rb[2], ka[2], kb[2];
  stage_load<false>(keys + k0, NK_, scp, skl4, ka, kb);
  stage_load<true >(dist + k0, QNK_, scp, skl4, ra, rb);    // q=0
  stage_write(k_lds, scp, skl4, ka, kb);
  __syncthreads();

  f32x4 bk[2][2];
#pragma unroll
  for (int cf = 0; cf < 2; cf++)
#pragma unroll
    for (int of = 0; of < 2; of++){ f32x4 z = {0.f,0.f,0.f,0.f}; bk[cf][of] = z; }
#pragma unroll
  for (int ks = 0; ks < 4; ks++){
#pragma unroll
    for (int cf = 0; cf < 2; cf++){
      const bf16x8 b = frag_read(k_lds, cf, ks, g, li);
      bk[cf][0] = __builtin_amdgcn_mfma_f32_16x16x32_bf16(afr[ks*2+0], b, bk[cf][0], 0,0,0);
      bk[cf][1] = __builtin_amdgcn_mfma_f32_16x16x32_bf16(afr[ks*2+1], b, bk[cf][1], 0,0,0);
    }
  }

  stage_write(d_lds[0], scp, skl4, ra, rb);
  stage_load<true>(dist + NK_ + k0, QNK_, scp, skl4, ra, rb);  // q=1
  __syncthreads();

  float minv = INFINITY;

  for (int q = 0; q < NQ_; q++){
    const unsigned short* db = d_lds[q & 1];
    f32x4 acc[2][2];
#pragma unroll
    for (int cf = 0; cf < 2; cf++)
#pragma unroll
      for (int of = 0; of < 2; of++) acc[cf][of] = bk[cf][of];

#pragma unroll
    for (int ks = 0; ks < 4; ks++){
#pragma unroll
      for (int cf = 0; cf < 2; cf++){
        const bf16x8 b = frag_read(db, cf, ks, g, li);
        acc[cf][0] = __builtin_amdgcn_mfma_f32_16x16x32_bf16(afr[8+ks*2+0], b, acc[cf][0], 0,0,0);
        acc[cf][1] = __builtin_amdgcn_mfma_f32_16x16x32_bf16(afr[8+ks*2+1], b, acc[cf][1], 0,0,0);
      }
    }

    const f32x4 aqv0 = *(const f32x4*)&aq_lds[q*128 + o0 + (g<<2)];
    const f32x4 aqv1 = *(const f32x4*)&aq_lds[q*128 + o0 + 16 + (g<<2)];
#pragma unroll
    for (int cf = 0; cf < 2; cf++){
      float s = 0.f;
#pragma unroll
      for (int r = 0; r < 4; r++){
        s += w2v0[r] * fmaxf(acc[cf][0][r] + aqv0[r], 0.f);
        s += w2v1[r] * fmaxf(acc[cf][1][r] + aqv1[r], 0.f);
      }
      s += __shfl_xor(s, 16, 64);
      s += __shfl_xor(s, 32, 64);
      if (l < 16) red[w][(cf<<4) + l] = s;
    }
    __syncthreads();

    if (q < 7){
      stage_write(d_lds[(q+1)&1], scp, skl4, ra, rb);
      if (q < 6) stage_load<true>(dist + (size_t)(q+2)*NK_ + k0, QNK_, scp, skl4, ra, rb);
    }
    if (t < 32){
      float s = b2v + red[0][t] + red[1][t] + red[2][t] + red[3][t];
      scores[(size_t)q*NK_ + k0 + t] = s;       // raw scores (floor applied later)
      minv = fminf(minv, s);
    }
    __syncthreads();
  }

  if (t < 32){
#pragma unroll
    for (int off = 16; off > 0; off >>= 1) minv = fminf(minv, __shfl_xor(minv, off, 64));
    if (t == 0) atomicMin((unsigned int*)(ws + MINKEY_OFF), fkey(minv));
  }
}

// ---------------- softmax + PV partials ----------------
__global__ __launch_bounds__(256) void softmax_pv_kernel(
    const float* __restrict__ value, const int* __restrict__ mask,
    float* __restrict__ scores, float* __restrict__ ws)
{
  __shared__ float v_lds[128*128];    // XOR-swizzled [d][k]
  __shared__ __align__(16) float e_lds[8][128];
  __shared__ float wsum[8];
  const int t = threadIdx.x, bid = blockIdx.x, k0 = bid*128;
  const float floorv = fkey_dec(*(const unsigned int*)(ws + MINKEY_OFF)) - 20.0f;

  for (int i = t; i < 4096; i += 256){
    const int d = i >> 5, k4 = (i & 31)*4;
    const f32x4 v = __builtin_nontemporal_load((const f32x4*)&value[(size_t)d*NK_ + k0 + k4]);
    const int dw = (d*128 + k4) ^ ((d & 31) << 2);
    *(f32x4*)&v_lds[dw] = v;
  }

  {
    const int q = t >> 5, kk = (t & 31)*4;
    const size_t gi = (size_t)q*NK_ + k0 + kk;
    const f32x4 s4 = *(const f32x4*)&scores[gi];
    const i32x4 m4 = *(const i32x4*)&mask[gi];
    f32x4 sf, e;
#pragma unroll
    for (int j = 0; j < 4; j++){
      sf[j] = m4[j] ? s4[j] : s4[j] + floorv;
      e[j]  = __expf(sf[j]);
    }
    *(f32x4*)&scores[gi] = sf;                 // final masked scores output
    *(f32x4*)&e_lds[q][kk] = e;
    float es = e[0] + e[1] + e[2] + e[3];
#pragma unroll
    for (int off = 16; off > 0; off >>= 1) es += __shfl_xor(es, off, 64);
    if ((t & 31) == 0) wsum[q] = es;
  }
  __syncthreads();
  if (t < 8) ws[DENOM_OFF + t*NCH_ + bid] = wsum[t];

  const int d = t & 127, qb = (t >> 7)*4;
  f32x4 acc = {0.f,0.f,0.f,0.f};
#pragma unroll 8
  for (int k4 = 0; k4 < 128; k4 += 4){
    const int dw = (d*128 + k4) ^ ((d & 31) << 2);
    const f32x4 v  = *(const f32x4*)&v_lds[dw];
    const f32x4 e0 = *(const f32x4*)&e_lds[qb+0][k4];
    const f32x4 e1 = *(const f32x4*)&e_lds[qb+1][k4];
    const f32x4 e2 = *(const f32x4*)&e_lds[qb+2][k4];
    const f32x4 e3 = *(const f32x4*)&e_lds[qb+3][k4];
#pragma unroll
    for (int j = 0; j < 4; j++){
      acc[0] += v[j]*e0[j]; acc[1] += v[j]*e1[j];
      acc[2] += v[j]*e2[j]; acc[3] += v[j]*e3[j];
    }
  }
#pragma unroll
  for (int j = 0; j < 4; j++) ws[OUTV_OFF + (size_t)bid*1024 + d*8 + qb + j] = acc[j];
}

// ---------------- finalize: 32 blocks, coalesced chunk reduce ----------------
__global__ __launch_bounds__(256) void finalize_kernel(const float* __restrict__ ws,
    float* __restrict__ out){
  __shared__ float dsum[8];
  __shared__ float red[8][32];
  const int t = threadIdx.x, bid = blockIdx.x;

  if (t < 64){
    const int q = t >> 3, i = t & 7;
    float s = 0.f;
    for (int j = 0; j < 32; j++) s += ws[DENOM_OFF + q*NCH_ + i + 8*j];
#pragma unroll
    for (int off = 4; off > 0; off >>= 1) s += __shfl_xor(s, off, 64);
    if (i == 0) dsum[q] = s;
  }

  const int ol = t & 31, part = t >> 5;
  float s = 0.f;
  for (int j = 0; j < 32; j++)
    s += ws[OUTV_OFF + (size_t)(part + 8*j)*1024 + bid*32 + ol];
  red[part][ol] = s;
  __syncthreads();

  if (t < 32){
    float a = 0.f;
#pragma unroll
    for (int p = 0; p < 8; p++) a += red[p][t];
    const int o = bid*32 + t;
    out[o] = a / dsum[o & 7];
  }
}

extern "C" void kernel_launch(void* const* d_in, const int* in_sizes, int n_in,
                              void* d_out, int out_size, void* d_ws, size_t ws_size,
                              hipStream_t stream){
  const float* query=(const float*)d_in[0];
  const float* keys =(const float*)d_in[1];
  const float* value=(const float*)d_in[2];
  const float* dist =(const float*)d_in[3];
  const int*   mask =(const int*)d_in[4];
  const float* W1   =(const float*)d_in[5];
  const float* b1   =(const float*)d_in[6];
  const float* W2   =(const float*)d_in[7];
  const float* b2   =(const float*)d_in[8];
  float* out=(float*)d_out;
  float* scores=out+1024;
  float* ws=(float*)d_ws;

  prep_kernel      <<<1,256,0,stream>>>(query,W1,b1,ws);
  scores_kernel    <<<NBLK_,256,0,stream>>>(keys,dist,W2,b2,ws,scores);
  softmax_pv_kernel<<<NCH_,256,0,stream>>>(value,mask,scores,ws);
  finalize_kernel  <<<32,256,0,stream>>>(ws,out);
}